// Round 4
// baseline (706.899 us; speedup 1.0000x reference)
//
#include <hip/hip_runtime.h>
#include <math.h>

#define H_DIM 1024
#define HH_DIM 512

typedef _Float16 half8 __attribute__((ext_vector_type(8)));
typedef float f32x4 __attribute__((ext_vector_type(4)));

__device__ __forceinline__ void gload_lds16(const void* g, void* l) {
    __builtin_amdgcn_global_load_lds((const __attribute__((address_space(1))) uint32_t*)g,
                                     (__attribute__((address_space(3))) uint32_t*)l,
                                     16, 0, 0);
}

// ---- pack W1 [512][1024] fp32 -> two fp16 planes in MFMA-fragment order ----
// Bpack element offset: ((ks*2 + p)*32 + nfrag)*512 + lane*8 + j
// lane holds B[k = ks*32 + (lane>>4)*8 + j][n = nfrag*16 + (lane&15)] = W1[n][k]
__global__ void pack_w1_kernel(const float* __restrict__ W1, _Float16* __restrict__ Bpack) {
    int tid  = blockIdx.x * 256 + threadIdx.x;   // 0..65535
    int lane = tid & 63;
    int nfg  = (tid >> 6) & 31;
    int ks   = tid >> 11;                        // 0..31
    int n    = nfg * 16 + (lane & 15);
    int k0   = ks * 32 + (lane >> 4) * 8;
    const float* src = W1 + (size_t)n * H_DIM + k0;
    float4 v0 = *(const float4*)src;
    float4 v1 = *(const float4*)(src + 4);
    float xs[8] = {v0.x, v0.y, v0.z, v0.w, v1.x, v1.y, v1.z, v1.w};
    half8 h0, h1;
#pragma unroll
    for (int j = 0; j < 8; ++j) {
        _Float16 a = (_Float16)xs[j];
        float r = xs[j] - (float)a;
        h0[j] = a;
        h1[j] = (_Float16)(r * 2048.0f);
    }
    size_t o0 = ((size_t)(ks * 2 + 0) * 32 + nfg) * 512 + lane * 8;
    size_t o1 = ((size_t)(ks * 2 + 1) * 32 + nfg) * 512 + lane * 8;
    *(half8*)(Bpack + o0) = h0;
    *(half8*)(Bpack + o1) = h1;
}

// ---- fused scorer via fp16-split MFMA ----
// block: 64 rows x 128 cols (nb quarter of N=512), 4 waves each 64x32.
// 3 blocks/CU (48 KB LDS, <=168 VGPR target), XCD-chunked block swizzle.
// LDS map:
//   As: [buf][pl][mf4][slot64][8]h  off = (((buf*2+pl)*4+mf)*64+slot)*16   [0,16384)
//   Bs: [buf][pl][nf8][slot64][8]h  off = 16384 + (((buf*2+pl)*8+nf)*64+slot)*16
//   red: float[4][64][17] overlays base (epilogue only)
__global__ __launch_bounds__(256, 3)
void score_mfma_kernel(const float* __restrict__ X,
                       const _Float16* __restrict__ Bpack,
                       const float* __restrict__ b1,
                       const float* __restrict__ W2,
                       float* __restrict__ sparts, int tot_tokens, int nblk) {
    __shared__ __align__(16) char smem[49152];

    const int t    = threadIdx.x;
    const int w    = t >> 6;
    const int lane = t & 63;

    // XCD-chunked swizzle: consecutive logical blocks (the 4 nb of one m-row)
    // land on the same XCD -> L2 serves the X re-reads.
    const int chunk   = nblk >> 3;                 // 1152
    const int logical = (blockIdx.x & 7) * chunk + (blockIdx.x >> 3);
    const int nb      = logical & 3;
    const size_t m0   = (size_t)(logical >> 2) * 64;

    // A staging: thread t -> row w*16+(t&15), k-quad (t>>4)&3; LDS slot t&63 (linear)
    const int arow  = w * 16 + (t & 15);
    const int aq    = (t >> 4) & 3;
    const int aslot = t & 63;
    const float* aptr = X + (m0 + arow) * H_DIM + aq * 8;

    f32x4 acc1[4][2] = {};
    f32x4 acc2[4][2] = {};

#define CONVERT_WRITE(buf)                                                          \
    do {                                                                            \
        float xs[8] = {av0.x, av0.y, av0.z, av0.w, av1.x, av1.y, av1.z, av1.w};     \
        half8 h0, h1;                                                               \
        _Pragma("unroll") for (int j = 0; j < 8; ++j) {                             \
            _Float16 a = (_Float16)xs[j];                                           \
            float r = xs[j] - (float)a;                                             \
            h0[j] = a;                                                              \
            h1[j] = (_Float16)(r * 2048.0f);                                        \
        }                                                                           \
        *(half8*)(smem + ((((buf) * 2 + 0) * 4 + w) * 64 + aslot) * 16) = h0;       \
        *(half8*)(smem + ((((buf) * 2 + 1) * 4 + w) * 64 + aslot) * 16) = h1;       \
    } while (0)

    // B stage: 16 KB = 2 planes x 8 nfrag x 1 KB; 4 x gload_lds16 per thread
#define STAGE_B(ks, buf)                                                            \
    do {                                                                            \
        char* bdst = smem + 16384 + (buf) * 16384;                                  \
        _Pragma("unroll") for (int r = 0; r < 4; ++r) {                             \
            int idx = r * 256 + t;          /* 0..1023 16B-chunks */                \
            int p   = idx >> 9;                                                     \
            int rem = idx & 511;                                                    \
            size_t src = ((size_t)((ks) * 2 + p) * 32 + nb * 8 + (rem >> 6)) * 512  \
                         + (rem & 63) * 8;                                          \
            gload_lds16(Bpack + src, bdst + (size_t)idx * 16);                      \
        }                                                                           \
    } while (0)

    // ---- prologue ----
    float4 av0 = *(const float4*)(aptr);
    float4 av1 = *(const float4*)(aptr + 4);
    CONVERT_WRITE(0);
    STAGE_B(0, 0);
    __builtin_amdgcn_sched_barrier(0);
    av0 = *(const float4*)(aptr + 32);
    av1 = *(const float4*)(aptr + 36);
    __builtin_amdgcn_sched_barrier(0);
    asm volatile("s_waitcnt vmcnt(2) lgkmcnt(0)" ::: "memory");
    __builtin_amdgcn_sched_barrier(0);
    __builtin_amdgcn_s_barrier();

    int cur = 0;
    for (int ks = 0; ks < 32; ++ks) {
        const int nxt = cur ^ 1;
        if (ks < 31) {
            STAGE_B(ks + 1, nxt);               // 4 gload_lds (oldest vmem)
            __builtin_amdgcn_sched_barrier(0);
            CONVERT_WRITE(nxt);                 // av holds A(ks+1)
            if (ks < 30) {                      // 2 newest vmem, stay in flight
                av0 = *(const float4*)(aptr + (ks + 2) * 32);
                av1 = *(const float4*)(aptr + (ks + 2) * 32 + 4);
            }
            __builtin_amdgcn_sched_barrier(0);
        }

        half8 aA[4], aB[4], bA[2], bB[2];
#pragma unroll
        for (int mf = 0; mf < 4; ++mf) {
            aA[mf] = *(const half8*)(smem + (((cur * 2 + 0) * 4 + mf) * 64 + lane) * 16);
            aB[mf] = *(const half8*)(smem + (((cur * 2 + 1) * 4 + mf) * 64 + lane) * 16);
        }
#pragma unroll
        for (int nf = 0; nf < 2; ++nf) {
            bA[nf] = *(const half8*)(smem + 16384 + cur * 16384 + (((0) * 8 + w * 2 + nf) * 64 + lane) * 16);
            bB[nf] = *(const half8*)(smem + 16384 + cur * 16384 + (((1) * 8 + w * 2 + nf) * 64 + lane) * 16);
        }

        __builtin_amdgcn_s_setprio(1);
#pragma unroll
        for (int mf = 0; mf < 4; ++mf)
#pragma unroll
            for (int nf = 0; nf < 2; ++nf)
                acc1[mf][nf] = __builtin_amdgcn_mfma_f32_16x16x32_f16(aA[mf], bA[nf], acc1[mf][nf], 0, 0, 0);
#pragma unroll
        for (int mf = 0; mf < 4; ++mf)
#pragma unroll
            for (int nf = 0; nf < 2; ++nf)
                acc2[mf][nf] = __builtin_amdgcn_mfma_f32_16x16x32_f16(aA[mf], bB[nf], acc2[mf][nf], 0, 0, 0);
#pragma unroll
        for (int mf = 0; mf < 4; ++mf)
#pragma unroll
            for (int nf = 0; nf < 2; ++nf)
                acc2[mf][nf] = __builtin_amdgcn_mfma_f32_16x16x32_f16(aB[mf], bA[nf], acc2[mf][nf], 0, 0, 0);
        __builtin_amdgcn_s_setprio(0);

        if (ks < 31) {
            if (ks < 30) {
                asm volatile("s_waitcnt vmcnt(2) lgkmcnt(0)" ::: "memory");
            } else {
                asm volatile("s_waitcnt vmcnt(0) lgkmcnt(0)" ::: "memory");
            }
            __builtin_amdgcn_sched_barrier(0);
            __builtin_amdgcn_s_barrier();
        }
        cur = nxt;
    }

    // ---- epilogue: h = acc1 + acc2/2048 + b1; gelu; *W2; reduce over 128 cols ----
    __syncthreads();  // all frag reads done before red overlays As/Bs
    float* red = (float*)smem;  // [4][64][17]
    const int hi = lane >> 4;
    const int lc = lane & 15;
    float b1v[2], w2v[2];
#pragma unroll
    for (int nf = 0; nf < 2; ++nf) {
        int c = nb * 128 + w * 32 + nf * 16 + lc;
        b1v[nf] = b1[c];
        w2v[nf] = W2[c];
    }
#pragma unroll
    for (int mf = 0; mf < 4; ++mf) {
#pragma unroll
        for (int i = 0; i < 4; ++i) {
            float s = 0.f;
#pragma unroll
            for (int nf = 0; nf < 2; ++nf) {
                float h = acc1[mf][nf][i] + acc2[mf][nf][i] * (1.0f / 2048.0f) + b1v[nf];
                float g = 0.5f * h * (1.0f + erff(h * 0.70710678118654752f));
                s = fmaf(g, w2v[nf], s);
            }
            red[(w * 64 + mf * 16 + hi * 4 + i) * 17 + lc] = s;
        }
    }
    __syncthreads();
    if (t < 64) {
        float s = 0.f;
#pragma unroll
        for (int ww = 0; ww < 4; ++ww)
#pragma unroll
            for (int c = 0; c < 16; ++c) s += red[(ww * 64 + t) * 17 + c];
        sparts[(size_t)nb * tot_tokens + m0 + t] = s;
    }
}

// ---- per-segment top-quota selection + gather (scores = sum of 4 partials) ----
__global__ void select_gather_kernel(const float* __restrict__ X,
                                     const float* __restrict__ sparts,
                                     float* __restrict__ out,
                                     int N, int seg_len, int quota, int n_seg,
                                     int tot_tokens) {
    const int seg = blockIdx.x;
    const int b   = blockIdx.y;
    __shared__ float sc[64];
    __shared__ int sel_idx[64];
    const int t = threadIdx.x;
    if (t < seg_len) {
        size_t tok = (size_t)b * N + (size_t)seg * seg_len + t;
        sc[t] = sparts[tok] + sparts[tok + tot_tokens]
              + sparts[tok + 2 * (size_t)tot_tokens] + sparts[tok + 3 * (size_t)tot_tokens];
    }
    __syncthreads();
    if (t == 0) {
        unsigned long long mask = 0ull;
        for (int it = 0; it < quota; ++it) {
            float best = 0.f;
            int bi = 0;
            bool found = false;
            for (int i = 0; i < seg_len; ++i) {
                if (!((mask >> i) & 1ull)) {
                    if (!found || sc[i] > best) { best = sc[i]; bi = i; found = true; }
                }
            }
            mask |= (1ull << bi);
        }
        int c = 0;
        for (int i = 0; i < seg_len; ++i)
            if ((mask >> i) & 1ull) sel_idx[c++] = i;  // ascending == sorted output
    }
    __syncthreads();
    const size_t HV = H_DIM / 4;
    const float4* xb = (const float4*)X + ((size_t)b * N + (size_t)seg * seg_len) * HV;
    float4* ob = (float4*)out + ((size_t)b * n_seg * quota + (size_t)seg * quota) * HV;
    for (int j = 0; j < quota; ++j) {
        const float4* srow = xb + (size_t)sel_idx[j] * HV;
        float4* drow = ob + (size_t)j * HV;
        for (int c = t; c < (int)HV; c += blockDim.x) drow[c] = srow[c];
    }
}

extern "C" void kernel_launch(void* const* d_in, const int* in_sizes, int n_in,
                              void* d_out, int out_size, void* d_ws, size_t ws_size,
                              hipStream_t stream) {
    const float* X  = (const float*)d_in[0];
    const float* W1 = (const float*)d_in[1];
    const float* b1 = (const float*)d_in[2];
    const float* W2 = (const float*)d_in[3];
    float* out = (float*)d_out;

    const int Hh = in_sizes[2];                        // 512
    const int H  = Hh * 2;                             // 1024
    const long long TOT = (long long)in_sizes[0] / H;  // 147456 tokens
    const int B = 256;
    const int N = (int)(TOT / B);                      // 576
    const int n_seg = 32;
    const int seg_len = N / n_seg;                     // 18
    const int rows_per_b = out_size / (B * H);         // 288
    const int quota = rows_per_b / n_seg;              // 9

    _Float16* Bpack = (_Float16*)d_ws;                                  // 2 MB
    float* sparts   = (float*)((char*)d_ws + (size_t)2 * 1024 * 1024);  // 4*TOT floats

    hipLaunchKernelGGL(pack_w1_kernel, dim3(256), dim3(256), 0, stream, W1, Bpack);

    const int nblk = (int)(TOT / 64) * 4;              // 9216, divisible by 8
    hipLaunchKernelGGL(score_mfma_kernel, dim3(nblk), dim3(256), 0, stream,
                       X, Bpack, b1, W2, sparts, (int)TOT, nblk);

    dim3 sg(n_seg, B);
    hipLaunchKernelGGL(select_gather_kernel, sg, dim3(256), 0, stream,
                       X, sparts, out, N, seg_len, quota, n_seg, (int)TOT);
}